// Round 13
// baseline (166.591 us; speedup 1.0000x reference)
//
#include <hip/hip_runtime.h>

typedef __bf16 bf16_t;
typedef __bf16 bf16x4 __attribute__((ext_vector_type(4)));
typedef __bf16 bf16x8 __attribute__((ext_vector_type(8)));
typedef float floatx4 __attribute__((ext_vector_type(4)));

static constexpr int NN  = 8192;
static constexpr int FIN = 512;
static constexpr int NH1 = 256;
static constexpr int NH2 = 128;
static constexpr int NE  = 262144;
static constexpr int CAP = 128;   // bucket capacity per row (mean deg 32, P(>128)~e^-70)

// output layout (floats): h1, adj_rec, mu, logvar, z
static constexpr size_t OFF_H1     = 0;
static constexpr size_t OFF_ADJ    = (size_t)NN * NH1;
static constexpr size_t OFF_MU     = OFF_ADJ + (size_t)NN * NN;
static constexpr size_t OFF_LOGVAR = OFF_MU + (size_t)NN * NH2;
static constexpr size_t OFF_Z      = OFF_LOGVAR + (size_t)NN * NH2;

// ---------------- generic GEMM body (R7 path, bf16 MFMA, f32 acc) ----------------
// Block tile (RT*32) x 128, 4 waves 2x2, wave tile (RT*16) x 64.
// A/B frags share the same lane->k map -> exact for any HW k-order.
// Epilogue: per-rt 16x64 scalar transpose through per-wave LDS -> vector stores.
// EPI: 1 = mu/z/logvar f32 nt + zbf bf16   2 = bf16 only
template <int KD, int RT, bool ABF, int EPI>
__device__ __forceinline__ void gemm_body(
    int bx, int by, const float* __restrict__ Af, const bf16_t* __restrict__ Abf,
    const bf16_t* __restrict__ BT, float* __restrict__ dout,
    bf16_t* __restrict__ zb, int ldz, float* __restrict__ L, int lane, int wid) {
  const int l15 = lane & 15;
  const int lg  = lane >> 4;
  const int brow = by * (RT * 32) + (wid >> 1) * (RT * 16);
  const int bcol = bx * 128 + (wid & 1) * 64;

  floatx4 acc[RT][4];
#pragma unroll
  for (int i = 0; i < RT; ++i)
#pragma unroll
    for (int j = 0; j < 4; ++j) acc[i][j] = (floatx4){0.f, 0.f, 0.f, 0.f};

#pragma unroll 1
  for (int kk = 0; kk < KD; kk += 32) {
    bf16x8 a[RT], b[4];
#pragma unroll
    for (int rt = 0; rt < RT; ++rt) {
      const int r = brow + rt * 16 + l15;
      if constexpr (ABF) {
        a[rt] = *(const bf16x8*)(Abf + (size_t)r * KD + kk + lg * 8);
      } else {
        const float* p = Af + (size_t)r * KD + kk + lg * 8;
        const floatx4 lo = *(const floatx4*)p;
        const floatx4 hi = *(const floatx4*)(p + 4);
        bf16x8 t;
        t[0] = (bf16_t)lo[0]; t[1] = (bf16_t)lo[1];
        t[2] = (bf16_t)lo[2]; t[3] = (bf16_t)lo[3];
        t[4] = (bf16_t)hi[0]; t[5] = (bf16_t)hi[1];
        t[6] = (bf16_t)hi[2]; t[7] = (bf16_t)hi[3];
        a[rt] = t;
      }
    }
#pragma unroll
    for (int ct = 0; ct < 4; ++ct) {
      const int c = bcol + ct * 16 + l15;
      b[ct] = *(const bf16x8*)(BT + (size_t)c * KD + kk + lg * 8);
    }
#pragma unroll
    for (int rt = 0; rt < RT; ++rt)
#pragma unroll
      for (int ct = 0; ct < 4; ++ct)
        acc[rt][ct] = __builtin_amdgcn_mfma_f32_16x16x32_bf16(
            a[rt], b[ct], acc[rt][ct], 0, 0, 0);
  }

#pragma unroll
  for (int rt = 0; rt < RT; ++rt) {
#pragma unroll
    for (int ct = 0; ct < 4; ++ct)
#pragma unroll
      for (int r = 0; r < 4; ++r)
        L[(lg * 4 + r) * 68 + ct * 16 + l15] = acc[rt][ct][r];
    __builtin_amdgcn_wave_barrier();
#pragma unroll
    for (int it = 0; it < 4; ++it) {
      const int idx = it * 64 + lane;
      const int rr = idx >> 4, c4 = idx & 15;
      const floatx4 v = *(const floatx4*)(L + rr * 68 + c4 * 4);
      const int orow = brow + rt * 16 + rr;
      const int gc = bcol + c4 * 4;
      if constexpr (EPI == 1) {
        if (gc < NH2) {
          __builtin_nontemporal_store(
              v, (floatx4*)(dout + OFF_MU + (size_t)orow * NH2 + gc));
          __builtin_nontemporal_store(
              v, (floatx4*)(dout + OFF_Z + (size_t)orow * NH2 + gc));
          bf16x4 o;
          o[0] = (bf16_t)v[0]; o[1] = (bf16_t)v[1];
          o[2] = (bf16_t)v[2]; o[3] = (bf16_t)v[3];
          *(bf16x4*)(zb + (size_t)orow * ldz + gc) = o;
        } else {
          __builtin_nontemporal_store(
              v, (floatx4*)(dout + OFF_LOGVAR + (size_t)orow * NH2 + gc - NH2));
        }
      } else {
        bf16x4 o;
        o[0] = (bf16_t)v[0]; o[1] = (bf16_t)v[1];
        o[2] = (bf16_t)v[2]; o[3] = (bf16_t)v[3];
        *(bf16x4*)(zb + (size_t)orow * ldz + gc) = o;
      }
    }
    __builtin_amdgcn_wave_barrier();
  }
}

// ---------------- dedicated adj kernel: 64x128 tile, 4 blocks/CU ----------------
// RT=2 -> acc 32 VGPR; __launch_bounds__(256,4) pins <=128 VGPR -> 16 waves/CU.
// Swapped mfma(b,a,acc): acc[rt][ct] = 4 consecutive cols of row brow+rt*16+l15.
// Epilogue: b128 XOR-swizzled LDS staging -> 256B nt store segments.
__global__ __launch_bounds__(256, 4) void adj_gemm(
    const bf16_t* __restrict__ zb, float* __restrict__ C) {
  __shared__ float lt[4][1024];  // 16 KB
  const int bid = blockIdx.x;                    // 8192 blocks
  const int s = (bid & 7) * 1024 + (bid >> 3);   // XCD-contiguous panels
  const int by = s >> 6, bx = s & 63;            // 128 row-tiles x 64 col-tiles
  const int lane = threadIdx.x & 63;
  const int wid  = threadIdx.x >> 6;
  const int l15 = lane & 15;
  const int lg  = lane >> 4;
  const int brow = by * 64 + (wid >> 1) * 32;
  const int bcol = bx * 128 + (wid & 1) * 64;
  float* L = lt[wid];

  floatx4 acc[2][4];
#pragma unroll
  for (int i = 0; i < 2; ++i)
#pragma unroll
    for (int j = 0; j < 4; ++j) acc[i][j] = (floatx4){0.f, 0.f, 0.f, 0.f};

#pragma unroll 2
  for (int kk = 0; kk < NH2; kk += 32) {
    bf16x8 a[2], b[4];
#pragma unroll
    for (int rt = 0; rt < 2; ++rt)
      a[rt] = *(const bf16x8*)(zb + (size_t)(brow + rt * 16 + l15) * NH2 + kk +
                               lg * 8);
#pragma unroll
    for (int ct = 0; ct < 4; ++ct)
      b[ct] = *(const bf16x8*)(zb + (size_t)(bcol + ct * 16 + l15) * NH2 + kk +
                               lg * 8);
#pragma unroll
    for (int rt = 0; rt < 2; ++rt)
#pragma unroll
      for (int ct = 0; ct < 4; ++ct)
        acc[rt][ct] = __builtin_amdgcn_mfma_f32_16x16x32_bf16(
            b[ct], a[rt], acc[rt][ct], 0, 0, 0);  // SWAPPED
  }

#pragma unroll
  for (int rt = 0; rt < 2; ++rt) {
#pragma unroll
    for (int ct = 0; ct < 4; ++ct) {
      const int phys = (ct * 4 + lg) ^ l15;
      *(floatx4*)(L + l15 * 64 + phys * 4) = acc[rt][ct];
    }
    __builtin_amdgcn_wave_barrier();
#pragma unroll
    for (int it = 0; it < 4; ++it) {
      const int row = it * 4 + lg;
      const int phys = l15 ^ row;
      const floatx4 v = *(const floatx4*)(L + row * 64 + phys * 4);
      __builtin_nontemporal_store(
          v, (floatx4*)(C + (size_t)(brow + rt * 16 + row) * NN + bcol + l15 * 4));
    }
    __builtin_amdgcn_wave_barrier();
  }
}

// ---------------- K0: zero counts/spill + weight transpose to bf16 ----------------
__global__ __launch_bounds__(256) void k_prep(
    const float* __restrict__ W1, const float* __restrict__ W2,
    const float* __restrict__ W3, bf16_t* __restrict__ W1T,
    bf16_t* __restrict__ W23T, int* __restrict__ counts) {
  const int gid = blockIdx.x * 256 + threadIdx.x;  // grid 512 -> 131072 threads
  if (gid <= NN) counts[gid] = 0;                  // counts[NN] = spill counter
  if (gid < NH1 * FIN) {
    const int n = gid >> 9, k = gid & 511;
    W1T[gid] = (bf16_t)W1[k * NH1 + n];
  }
  if (gid < NH1 * NH1) {
    const int n = gid >> 8, k = gid & 255;
    W23T[gid] = (bf16_t)(n < NH2 ? W2[k * NH2 + n] : W3[k * NH2 + (n - NH2)]);
  }
}

// ---------------- K1 fat: gemm1 (blocks 0..255) || bucket fill (256..1279) ----------------
__global__ __launch_bounds__(256) void k_fat(
    const float* __restrict__ x, const bf16_t* __restrict__ W1T,
    bf16_t* __restrict__ XWb, const int* __restrict__ row,
    const int* __restrict__ col, const float* __restrict__ edge_w,
    int* __restrict__ counts, uint2* __restrict__ bucket,
    uint4* __restrict__ spill) {
  __shared__ float lt[4][16 * 68];
  const int bid = blockIdx.x;
  if (bid < 256) {
    const int lane = threadIdx.x & 63;
    const int wid  = threadIdx.x >> 6;
    gemm_body<FIN, 2, false, 2>(bid & 1, bid >> 1, x, nullptr, W1T, nullptr,
                                XWb, NH1, lt[wid], lane, wid);
  } else {
    const int e = (bid - 256) * 256 + threadIdx.x;  // 1024*256 == NE
    const int r = row[e];
    const int p = atomicAdd(&counts[r], 1);
    if (p < CAP) {
      uint2 v;
      v.x = (unsigned)col[e];
      v.y = __float_as_uint(edge_w[e]);
      bucket[(size_t)r * CAP + p] = v;
    } else {  // never in practice; correctness fallback
      const int s = atomicAdd(&counts[NN], 1);
      uint4 v;
      v.x = (unsigned)r; v.y = (unsigned)col[e];
      v.z = __float_as_uint(edge_w[e]); v.w = 0;
      spill[s] = v;
    }
  }
}

// ---------------- SPMM from buckets, d=256: one wave per row ----------------
template <bool RELU>
__global__ __launch_bounds__(256) void spmm_bucket(
    const int* __restrict__ counts, const uint2* __restrict__ bucket,
    const uint4* __restrict__ spill, const bf16_t* __restrict__ src,
    float* __restrict__ dst_f, bf16_t* __restrict__ dst_b) {
  const int lane = threadIdx.x & 63;
  const int r = blockIdx.x * 4 + (threadIdx.x >> 6);
  const int li = lane & 15;  // channel group [li*16, li*16+16)
  const int g  = lane >> 4;  // edge slot 0..3
  const int deg = min(counts[r], CAP);
  float acc[16];
#pragma unroll
  for (int c = 0; c < 16; ++c) acc[c] = 0.f;

  for (int base = 0; base < deg; base += 64) {
    const int t = base + lane;
    uint2 cw;
    cw.x = 0; cw.y = 0;
    if (t < deg) cw = bucket[(size_t)r * CAP + t];
    const int cnt = min(64, deg - base);
#pragma unroll 2
    for (int j4 = 0; j4 < cnt; j4 += 4) {
      const int cj = __shfl((int)cw.x, j4 + g);
      const float wj = __shfl(__uint_as_float(cw.y), j4 + g);
      const bf16_t* p = src + (size_t)cj * NH1 + li * 16;
      const bf16x8 v0 = *(const bf16x8*)p;
      const bf16x8 v1 = *(const bf16x8*)(p + 8);
#pragma unroll
      for (int c = 0; c < 8; ++c) {
        acc[c]     += wj * (float)v0[c];
        acc[8 + c] += wj * (float)v1[c];
      }
    }
  }
  // spill fallback (counts[NN]==0 in practice; one cached load)
  const int ns = counts[NN];
  if (ns > 0 && g == 0) {
    for (int i = 0; i < ns; ++i) {
      const uint4 s = spill[i];
      if ((int)s.x == r) {
        const float wj = __uint_as_float(s.z);
        const bf16_t* p = src + (size_t)s.y * NH1 + li * 16;
        const bf16x8 v0 = *(const bf16x8*)p;
        const bf16x8 v1 = *(const bf16x8*)(p + 8);
#pragma unroll
        for (int c = 0; c < 8; ++c) {
          acc[c]     += wj * (float)v0[c];
          acc[8 + c] += wj * (float)v1[c];
        }
      }
    }
  }
#pragma unroll
  for (int c = 0; c < 16; ++c) {
    acc[c] += __shfl_xor(acc[c], 16);
    acc[c] += __shfl_xor(acc[c], 32);
    if constexpr (RELU) acc[c] = fmaxf(acc[c], 0.f);
  }
  float o0, o1, o2, o3;
  switch (g) {
    case 0:  o0 = acc[0];  o1 = acc[1];  o2 = acc[2];  o3 = acc[3];  break;
    case 1:  o0 = acc[4];  o1 = acc[5];  o2 = acc[6];  o3 = acc[7];  break;
    case 2:  o0 = acc[8];  o1 = acc[9];  o2 = acc[10]; o3 = acc[11]; break;
    default: o0 = acc[12]; o1 = acc[13]; o2 = acc[14]; o3 = acc[15]; break;
  }
  const int ch = li * 16 + g * 4;
  if (dst_f) {
    floatx4 o = (floatx4){o0, o1, o2, o3};
    __builtin_nontemporal_store(o, (floatx4*)(dst_f + (size_t)r * NH1 + ch));
  }
  if (dst_b) {
    bf16x4 o;
    o[0] = (bf16_t)o0; o[1] = (bf16_t)o1; o[2] = (bf16_t)o2; o[3] = (bf16_t)o3;
    *(bf16x4*)(dst_b + (size_t)r * NH1 + ch) = o;
  }
}

// ---------------- standalone GEMM wrapper (K4) ----------------
template <int KD, int RT, bool ABF, int EPI>
__global__ __launch_bounds__(256) void mfma_gemm(
    const float* __restrict__ Af, const bf16_t* __restrict__ Abf,
    const bf16_t* __restrict__ BT, float* __restrict__ dout,
    bf16_t* __restrict__ zb, int ldz) {
  __shared__ float lt[4][16 * 68];
  const int lane = threadIdx.x & 63;
  const int wid  = threadIdx.x >> 6;
  gemm_body<KD, RT, ABF, EPI>(blockIdx.x, blockIdx.y, Af, Abf, BT, dout, zb,
                              ldz, lt[wid], lane, wid);
}

extern "C" void kernel_launch(void* const* d_in, const int* in_sizes, int n_in,
                              void* d_out, int out_size, void* d_ws, size_t ws_size,
                              hipStream_t stream) {
  const float* x      = (const float*)d_in[0];
  const float* W1     = (const float*)d_in[1];
  const float* W2     = (const float*)d_in[2];
  const float* W3     = (const float*)d_in[3];
  const float* edge_w = (const float*)d_in[4];
  const int*   row    = (const int*)d_in[5];
  const int*   col    = (const int*)d_in[6];
  float* out = (float*)d_out;
  char*  ws  = (char*)d_ws;

  // ws layout (~17.1 MB), with overlays: gb reuses XWb, zbf reuses h1b
  bf16_t* XWb  = (bf16_t*)(ws);                          // 4 MB; later gb
  bf16_t* h1b  = (bf16_t*)(ws + (4u << 20));             // 4 MB; later zbf
  bf16_t* W1T  = (bf16_t*)(ws + (8u << 20));             // 256 KB
  bf16_t* W23T = (bf16_t*)(ws + (8u << 20) + (1u << 18));// 128 KB
  int*    counts = (int*)(ws + (8u << 20) + (3u << 18)); // (NN+1)*4B
  uint2*  bucket = (uint2*)(ws + (9u << 20));            // 8 MB (CAP=128)
  uint4*  spill  = (uint4*)(ws + (17u << 20));           // 64 KB
  bf16_t* gb  = XWb;
  bf16_t* zbf = h1b;

  // K0: zero counts + weight transpose
  k_prep<<<512, 256, 0, stream>>>(W1, W2, W3, W1T, W23T, counts);
  // K1: gemm1 (XWb = bf16(x@W1)) || bucket fill
  k_fat<<<1280, 256, 0, stream>>>(x, W1T, XWb, row, col, edge_w, counts, bucket,
                                  spill);
  // K2: h1 = relu(A . XWb) -> out f32 (nt) + h1b
  spmm_bucket<true><<<NN / 4, 256, 0, stream>>>(counts, bucket, spill, XWb,
                                                out + OFF_H1, h1b);
  // K3: gb = bf16(A . h1b)   (gb overlays XWb, which is dead now)
  spmm_bucket<false><<<NN / 4, 256, 0, stream>>>(counts, bucket, spill, h1b,
                                                 nullptr, gb);
  // K4: [mu|logvar] = gb @ [W2|W3] -> mu/z/logvar f32 (nt) + zbf (overlays h1b)
  mfma_gemm<NH1, 2, true, 1><<<dim3(2, 128), 256, 0, stream>>>(
      nullptr, gb, W23T, out, zbf, NH2);
  // K5: adj = z @ z^T, 64x128 tiles, 4 blocks/CU, XCD-swizzled
  adj_gemm<<<8192, 256, 0, stream>>>(zbf, out + OFF_ADJ);
}

// Round 14
// 162.591 us; speedup vs baseline: 1.0246x; 1.0246x over previous
//
#include <hip/hip_runtime.h>

typedef __bf16 bf16_t;
typedef __bf16 bf16x4 __attribute__((ext_vector_type(4)));
typedef __bf16 bf16x8 __attribute__((ext_vector_type(8)));
typedef float floatx4 __attribute__((ext_vector_type(4)));

static constexpr int NN  = 8192;
static constexpr int FIN = 512;
static constexpr int NH1 = 256;
static constexpr int NH2 = 128;
static constexpr int NE  = 262144;
static constexpr int CAP = 128;   // bucket capacity per row (mean deg 32, P(>128)~e^-70)

// output layout (floats): h1, adj_rec, mu, logvar, z
static constexpr size_t OFF_H1     = 0;
static constexpr size_t OFF_ADJ    = (size_t)NN * NH1;
static constexpr size_t OFF_MU     = OFF_ADJ + (size_t)NN * NN;
static constexpr size_t OFF_LOGVAR = OFF_MU + (size_t)NN * NH2;
static constexpr size_t OFF_Z      = OFF_LOGVAR + (size_t)NN * NH2;

// ---------------- GEMM body (bf16 MFMA, f32 acc) ---- R7 exact ----
template <int KD, int RT, bool ABF, int EPI>
__device__ __forceinline__ void gemm_body(
    int bx, int by, const float* __restrict__ Af, const bf16_t* __restrict__ Abf,
    const bf16_t* __restrict__ BT, float* __restrict__ C, int ldc,
    float* __restrict__ dout, bf16_t* __restrict__ zb, int ldz,
    float* __restrict__ L, int lane, int wid) {
  const int l15 = lane & 15;
  const int lg  = lane >> 4;
  const int brow = by * (RT * 32) + (wid >> 1) * (RT * 16);
  const int bcol = bx * 128 + (wid & 1) * 64;

  floatx4 acc[RT][4];
#pragma unroll
  for (int i = 0; i < RT; ++i)
#pragma unroll
    for (int j = 0; j < 4; ++j) acc[i][j] = (floatx4){0.f, 0.f, 0.f, 0.f};

#pragma unroll 1
  for (int kk = 0; kk < KD; kk += 32) {
    bf16x8 a[RT], b[4];
#pragma unroll
    for (int rt = 0; rt < RT; ++rt) {
      const int r = brow + rt * 16 + l15;
      if constexpr (ABF) {
        a[rt] = *(const bf16x8*)(Abf + (size_t)r * KD + kk + lg * 8);
      } else {
        const float* p = Af + (size_t)r * KD + kk + lg * 8;
        const floatx4 lo = *(const floatx4*)p;
        const floatx4 hi = *(const floatx4*)(p + 4);
        bf16x8 t;
        t[0] = (bf16_t)lo[0]; t[1] = (bf16_t)lo[1];
        t[2] = (bf16_t)lo[2]; t[3] = (bf16_t)lo[3];
        t[4] = (bf16_t)hi[0]; t[5] = (bf16_t)hi[1];
        t[6] = (bf16_t)hi[2]; t[7] = (bf16_t)hi[3];
        a[rt] = t;
      }
    }
#pragma unroll
    for (int ct = 0; ct < 4; ++ct) {
      const int c = bcol + ct * 16 + l15;
      b[ct] = *(const bf16x8*)(BT + (size_t)c * KD + kk + lg * 8);
    }
#pragma unroll
    for (int rt = 0; rt < RT; ++rt)
#pragma unroll
      for (int ct = 0; ct < 4; ++ct)
        acc[rt][ct] = __builtin_amdgcn_mfma_f32_16x16x32_bf16(
            a[rt], b[ct], acc[rt][ct], 0, 0, 0);
  }

#pragma unroll
  for (int rt = 0; rt < RT; ++rt) {
#pragma unroll
    for (int ct = 0; ct < 4; ++ct)
#pragma unroll
      for (int r = 0; r < 4; ++r)
        L[(lg * 4 + r) * 68 + ct * 16 + l15] = acc[rt][ct][r];
    __builtin_amdgcn_wave_barrier();
#pragma unroll
    for (int it = 0; it < 4; ++it) {
      const int idx = it * 64 + lane;
      const int rr = idx >> 4, c4 = idx & 15;
      const floatx4 v = *(const floatx4*)(L + rr * 68 + c4 * 4);
      const int orow = brow + rt * 16 + rr;
      const int gc = bcol + c4 * 4;
      if constexpr (EPI == 0) {
        __builtin_nontemporal_store(v, (floatx4*)(C + (size_t)orow * ldc + gc));
      } else if constexpr (EPI == 1) {
        if (gc < NH2) {
          __builtin_nontemporal_store(
              v, (floatx4*)(dout + OFF_MU + (size_t)orow * NH2 + gc));
          __builtin_nontemporal_store(
              v, (floatx4*)(dout + OFF_Z + (size_t)orow * NH2 + gc));
          bf16x4 o;
          o[0] = (bf16_t)v[0]; o[1] = (bf16_t)v[1];
          o[2] = (bf16_t)v[2]; o[3] = (bf16_t)v[3];
          *(bf16x4*)(zb + (size_t)orow * ldz + gc) = o;
        } else {
          __builtin_nontemporal_store(
              v, (floatx4*)(dout + OFF_LOGVAR + (size_t)orow * NH2 + gc - NH2));
        }
      } else {
        bf16x4 o;
        o[0] = (bf16_t)v[0]; o[1] = (bf16_t)v[1];
        o[2] = (bf16_t)v[2]; o[3] = (bf16_t)v[3];
        *(bf16x4*)(zb + (size_t)orow * ldz + gc) = o;
      }
    }
    __builtin_amdgcn_wave_barrier();
  }
}

// ---------------- K0: zero counts/spill + weight transpose to bf16 ----------------
__global__ __launch_bounds__(256) void k_prep(
    const float* __restrict__ W1, const float* __restrict__ W2,
    const float* __restrict__ W3, bf16_t* __restrict__ W1T,
    bf16_t* __restrict__ W23T, int* __restrict__ counts) {
  const int gid = blockIdx.x * 256 + threadIdx.x;
  if (gid <= NN) counts[gid] = 0;
  if (gid < NH1 * FIN) {
    const int n = gid >> 9, k = gid & 511;
    W1T[gid] = (bf16_t)W1[k * NH1 + n];
  }
  if (gid < NH1 * NH1) {
    const int n = gid >> 8, k = gid & 255;
    W23T[gid] = (bf16_t)(n < NH2 ? W2[k * NH2 + n] : W3[k * NH2 + (n - NH2)]);
  }
}

// ---------------- K1 fat: gemm1 (blocks 0..255) || bucket fill (256..1279) ----------------
__global__ __launch_bounds__(256) void k_fat(
    const float* __restrict__ x, const bf16_t* __restrict__ W1T,
    bf16_t* __restrict__ XWb, const int* __restrict__ row,
    const int* __restrict__ col, const float* __restrict__ edge_w,
    int* __restrict__ counts, uint2* __restrict__ bucket,
    uint4* __restrict__ spill) {
  __shared__ float lt[4][16 * 68];
  const int bid = blockIdx.x;
  if (bid < 256) {
    const int lane = threadIdx.x & 63;
    const int wid  = threadIdx.x >> 6;
    gemm_body<FIN, 2, false, 2>(bid & 1, bid >> 1, x, nullptr, W1T, nullptr, 0,
                                nullptr, XWb, NH1, lt[wid], lane, wid);
  } else {
    const int e = (bid - 256) * 256 + threadIdx.x;
    const int r = row[e];
    const int p = atomicAdd(&counts[r], 1);
    if (p < CAP) {
      uint2 v;
      v.x = (unsigned)col[e];
      v.y = __float_as_uint(edge_w[e]);
      bucket[(size_t)r * CAP + p] = v;
    } else {
      const int s = atomicAdd(&counts[NN], 1);
      uint4 v;
      v.x = (unsigned)r; v.y = (unsigned)col[e];
      v.z = __float_as_uint(edge_w[e]); v.w = 0;
      spill[s] = v;
    }
  }
}

// ---------------- SPMM from buckets, d=256: one wave per row ----------------
template <bool RELU>
__global__ __launch_bounds__(256) void spmm_bucket(
    const int* __restrict__ counts, const uint2* __restrict__ bucket,
    const uint4* __restrict__ spill, const bf16_t* __restrict__ src,
    float* __restrict__ dst_f, bf16_t* __restrict__ dst_b) {
  const int lane = threadIdx.x & 63;
  const int r = blockIdx.x * 4 + (threadIdx.x >> 6);
  const int li = lane & 15;
  const int g  = lane >> 4;
  const int deg = min(counts[r], CAP);
  float acc[16];
#pragma unroll
  for (int c = 0; c < 16; ++c) acc[c] = 0.f;

  for (int base = 0; base < deg; base += 64) {
    const int t = base + lane;
    uint2 cw;
    cw.x = 0; cw.y = 0;
    if (t < deg) cw = bucket[(size_t)r * CAP + t];
    const int cnt = min(64, deg - base);
#pragma unroll 2
    for (int j4 = 0; j4 < cnt; j4 += 4) {
      const int cj = __shfl((int)cw.x, j4 + g);
      const float wj = __shfl(__uint_as_float(cw.y), j4 + g);
      const bf16_t* p = src + (size_t)cj * NH1 + li * 16;
      const bf16x8 v0 = *(const bf16x8*)p;
      const bf16x8 v1 = *(const bf16x8*)(p + 8);
#pragma unroll
      for (int c = 0; c < 8; ++c) {
        acc[c]     += wj * (float)v0[c];
        acc[8 + c] += wj * (float)v1[c];
      }
    }
  }
  const int ns = counts[NN];
  if (ns > 0 && g == 0) {
    for (int i = 0; i < ns; ++i) {
      const uint4 s = spill[i];
      if ((int)s.x == r) {
        const float wj = __uint_as_float(s.z);
        const bf16_t* p = src + (size_t)s.y * NH1 + li * 16;
        const bf16x8 v0 = *(const bf16x8*)p;
        const bf16x8 v1 = *(const bf16x8*)(p + 8);
#pragma unroll
        for (int c = 0; c < 8; ++c) {
          acc[c]     += wj * (float)v0[c];
          acc[8 + c] += wj * (float)v1[c];
        }
      }
    }
  }
#pragma unroll
  for (int c = 0; c < 16; ++c) {
    acc[c] += __shfl_xor(acc[c], 16);
    acc[c] += __shfl_xor(acc[c], 32);
    if constexpr (RELU) acc[c] = fmaxf(acc[c], 0.f);
  }
  float o0, o1, o2, o3;
  switch (g) {
    case 0:  o0 = acc[0];  o1 = acc[1];  o2 = acc[2];  o3 = acc[3];  break;
    case 1:  o0 = acc[4];  o1 = acc[5];  o2 = acc[6];  o3 = acc[7];  break;
    case 2:  o0 = acc[8];  o1 = acc[9];  o2 = acc[10]; o3 = acc[11]; break;
    default: o0 = acc[12]; o1 = acc[13]; o2 = acc[14]; o3 = acc[15]; break;
  }
  const int ch = li * 16 + g * 4;
  if (dst_f) {
    floatx4 o = (floatx4){o0, o1, o2, o3};
    __builtin_nontemporal_store(o, (floatx4*)(dst_f + (size_t)r * NH1 + ch));
  }
  if (dst_b) {
    bf16x4 o;
    o[0] = (bf16_t)o0; o[1] = (bf16_t)o1; o[2] = (bf16_t)o2; o[3] = (bf16_t)o3;
    *(bf16x4*)(dst_b + (size_t)r * NH1 + ch) = o;
  }
}

// ---------------- standalone GEMM wrappers ----------------
template <int KD, int RT, bool ABF, int EPI, bool SWZ>
__global__ __launch_bounds__(256) void mfma_gemm(
    const float* __restrict__ Af, const bf16_t* __restrict__ Abf,
    const bf16_t* __restrict__ BT, float* __restrict__ C, int ldc,
    float* __restrict__ dout, bf16_t* __restrict__ zb, int ldz) {
  __shared__ float lt[4][16 * 68];
  int bx, by;
  if constexpr (SWZ) {
    const int bid = blockIdx.x;
    const int s = (bid & 7) * 512 + (bid >> 3);
    by = s >> 6; bx = s & 63;
  } else {
    bx = blockIdx.x; by = blockIdx.y;
  }
  const int lane = threadIdx.x & 63;
  const int wid  = threadIdx.x >> 6;
  gemm_body<KD, RT, ABF, EPI>(bx, by, Af, Abf, BT, C, ldc, dout, zb, ldz,
                              lt[wid], lane, wid);
}

extern "C" void kernel_launch(void* const* d_in, const int* in_sizes, int n_in,
                              void* d_out, int out_size, void* d_ws, size_t ws_size,
                              hipStream_t stream) {
  const float* x      = (const float*)d_in[0];
  const float* W1     = (const float*)d_in[1];
  const float* W2     = (const float*)d_in[2];
  const float* W3     = (const float*)d_in[3];
  const float* edge_w = (const float*)d_in[4];
  const int*   row    = (const int*)d_in[5];
  const int*   col    = (const int*)d_in[6];
  float* out = (float*)d_out;
  char*  ws  = (char*)d_ws;

  bf16_t* XWb  = (bf16_t*)(ws);
  bf16_t* h1b  = (bf16_t*)(ws + (4u << 20));
  bf16_t* W1T  = (bf16_t*)(ws + (8u << 20));
  bf16_t* W23T = (bf16_t*)(ws + (8u << 20) + (1u << 18));
  int*    counts = (int*)(ws + (8u << 20) + (3u << 18));
  uint2*  bucket = (uint2*)(ws + (9u << 20));
  uint4*  spill  = (uint4*)(ws + (17u << 20));
  bf16_t* gb  = XWb;
  bf16_t* zbf = h1b;

  // K0
  k_prep<<<512, 256, 0, stream>>>(W1, W2, W3, W1T, W23T, counts);
  // K1
  k_fat<<<1280, 256, 0, stream>>>(x, W1T, XWb, row, col, edge_w, counts, bucket,
                                  spill);
  // K2 -- LAUNCHED TWICE (idempotent): MEASUREMENT of T_K2 (+1 node)
  spmm_bucket<true><<<NN / 4, 256, 0, stream>>>(counts, bucket, spill, XWb,
                                                out + OFF_H1, h1b);
  spmm_bucket<true><<<NN / 4, 256, 0, stream>>>(counts, bucket, spill, XWb,
                                                out + OFF_H1, h1b);
  // K3 -- LAUNCHED TWICE (idempotent; runs after both K2s, overlays XWb)
  spmm_bucket<false><<<NN / 4, 256, 0, stream>>>(counts, bucket, spill, h1b,
                                                 nullptr, gb);
  spmm_bucket<false><<<NN / 4, 256, 0, stream>>>(counts, bucket, spill, h1b,
                                                 nullptr, gb);
  // K4
  mfma_gemm<NH1, 2, true, 1, false><<<dim3(2, 128), 256, 0, stream>>>(
      nullptr, gb, W23T, nullptr, 0, out, zbf, NH2);
  // K5: adj (R7 scheme, single launch)
  mfma_gemm<NH2, 4, true, 0, true><<<4096, 256, 0, stream>>>(
      nullptr, zbf, zbf, out + OFF_ADJ, NN, nullptr, nullptr, 0);
}

// Round 15
// 138.906 us; speedup vs baseline: 1.1993x; 1.1705x over previous
//
#include <hip/hip_runtime.h>

typedef __bf16 bf16_t;
typedef __bf16 bf16x4 __attribute__((ext_vector_type(4)));
typedef __bf16 bf16x8 __attribute__((ext_vector_type(8)));
typedef float floatx4 __attribute__((ext_vector_type(4)));

static constexpr int NN  = 8192;
static constexpr int FIN = 512;
static constexpr int NH1 = 256;
static constexpr int NH2 = 128;
static constexpr int NE  = 262144;
static constexpr int CAP = 128;   // bucket capacity per row (mean deg 32, P(>128)~e^-70)

// output layout (floats): h1, adj_rec, mu, logvar, z
static constexpr size_t OFF_H1     = 0;
static constexpr size_t OFF_ADJ    = (size_t)NN * NH1;
static constexpr size_t OFF_MU     = OFF_ADJ + (size_t)NN * NN;
static constexpr size_t OFF_LOGVAR = OFF_MU + (size_t)NN * NH2;
static constexpr size_t OFF_Z      = OFF_LOGVAR + (size_t)NN * NH2;

// ---------------- GEMM body (bf16 MFMA, f32 acc) ---- R7 exact ----
// EPI: 0 = f32 C nt (adj)   2 = bf16 only (XWb)
template <int KD, int RT, bool ABF, int EPI>
__device__ __forceinline__ void gemm_body(
    int bx, int by, const float* __restrict__ Af, const bf16_t* __restrict__ Abf,
    const bf16_t* __restrict__ BT, float* __restrict__ C, int ldc,
    bf16_t* __restrict__ zb, int ldz, float* __restrict__ L, int lane, int wid) {
  const int l15 = lane & 15;
  const int lg  = lane >> 4;
  const int brow = by * (RT * 32) + (wid >> 1) * (RT * 16);
  const int bcol = bx * 128 + (wid & 1) * 64;

  floatx4 acc[RT][4];
#pragma unroll
  for (int i = 0; i < RT; ++i)
#pragma unroll
    for (int j = 0; j < 4; ++j) acc[i][j] = (floatx4){0.f, 0.f, 0.f, 0.f};

#pragma unroll 1
  for (int kk = 0; kk < KD; kk += 32) {
    bf16x8 a[RT], b[4];
#pragma unroll
    for (int rt = 0; rt < RT; ++rt) {
      const int r = brow + rt * 16 + l15;
      if constexpr (ABF) {
        a[rt] = *(const bf16x8*)(Abf + (size_t)r * KD + kk + lg * 8);
      } else {
        const float* p = Af + (size_t)r * KD + kk + lg * 8;
        const floatx4 lo = *(const floatx4*)p;
        const floatx4 hi = *(const floatx4*)(p + 4);
        bf16x8 t;
        t[0] = (bf16_t)lo[0]; t[1] = (bf16_t)lo[1];
        t[2] = (bf16_t)lo[2]; t[3] = (bf16_t)lo[3];
        t[4] = (bf16_t)hi[0]; t[5] = (bf16_t)hi[1];
        t[6] = (bf16_t)hi[2]; t[7] = (bf16_t)hi[3];
        a[rt] = t;
      }
    }
#pragma unroll
    for (int ct = 0; ct < 4; ++ct) {
      const int c = bcol + ct * 16 + l15;
      b[ct] = *(const bf16x8*)(BT + (size_t)c * KD + kk + lg * 8);
    }
#pragma unroll
    for (int rt = 0; rt < RT; ++rt)
#pragma unroll
      for (int ct = 0; ct < 4; ++ct)
        acc[rt][ct] = __builtin_amdgcn_mfma_f32_16x16x32_bf16(
            a[rt], b[ct], acc[rt][ct], 0, 0, 0);
  }

#pragma unroll
  for (int rt = 0; rt < RT; ++rt) {
#pragma unroll
    for (int ct = 0; ct < 4; ++ct)
#pragma unroll
      for (int r = 0; r < 4; ++r)
        L[(lg * 4 + r) * 68 + ct * 16 + l15] = acc[rt][ct][r];
    __builtin_amdgcn_wave_barrier();
#pragma unroll
    for (int it = 0; it < 4; ++it) {
      const int idx = it * 64 + lane;
      const int rr = idx >> 4, c4 = idx & 15;
      const floatx4 v = *(const floatx4*)(L + rr * 68 + c4 * 4);
      const int orow = brow + rt * 16 + rr;
      const int gc = bcol + c4 * 4;
      if constexpr (EPI == 0) {
        __builtin_nontemporal_store(v, (floatx4*)(C + (size_t)orow * ldc + gc));
      } else {
        bf16x4 o;
        o[0] = (bf16_t)v[0]; o[1] = (bf16_t)v[1];
        o[2] = (bf16_t)v[2]; o[3] = (bf16_t)v[3];
        *(bf16x4*)(zb + (size_t)orow * ldz + gc) = o;
      }
    }
    __builtin_amdgcn_wave_barrier();
  }
}

// ---------------- K0: zero counts/spill + weight transpose to bf16 ----------------
__global__ __launch_bounds__(256) void k_prep(
    const float* __restrict__ W1, const float* __restrict__ W2,
    const float* __restrict__ W3, bf16_t* __restrict__ W1T,
    bf16_t* __restrict__ W23T, int* __restrict__ counts) {
  const int gid = blockIdx.x * 256 + threadIdx.x;
  if (gid <= NN) counts[gid] = 0;
  if (gid < NH1 * FIN) {
    const int n = gid >> 9, k = gid & 511;
    W1T[gid] = (bf16_t)W1[k * NH1 + n];
  }
  if (gid < NH1 * NH1) {
    const int n = gid >> 8, k = gid & 255;
    W23T[gid] = (bf16_t)(n < NH2 ? W2[k * NH2 + n] : W3[k * NH2 + (n - NH2)]);
  }
}

// ---------------- K1 fat: gemm1 (blocks 0..255) || bucket fill (256..1279) ----------------
__global__ __launch_bounds__(256) void k_fat(
    const float* __restrict__ x, const bf16_t* __restrict__ W1T,
    bf16_t* __restrict__ XWb, const int* __restrict__ row,
    const int* __restrict__ col, const float* __restrict__ edge_w,
    int* __restrict__ counts, uint2* __restrict__ bucket,
    uint4* __restrict__ spill) {
  __shared__ float lt[4][16 * 68];
  const int bid = blockIdx.x;
  if (bid < 256) {
    const int lane = threadIdx.x & 63;
    const int wid  = threadIdx.x >> 6;
    gemm_body<FIN, 2, false, 2>(bid & 1, bid >> 1, x, nullptr, W1T, nullptr, 0,
                                XWb, NH1, lt[wid], lane, wid);
  } else {
    const int e = (bid - 256) * 256 + threadIdx.x;
    const int r = row[e];
    const int p = atomicAdd(&counts[r], 1);
    if (p < CAP) {
      uint2 v;
      v.x = (unsigned)col[e];
      v.y = __float_as_uint(edge_w[e]);
      bucket[(size_t)r * CAP + p] = v;
    } else {
      const int s = atomicAdd(&counts[NN], 1);
      uint4 v;
      v.x = (unsigned)r; v.y = (unsigned)col[e];
      v.z = __float_as_uint(edge_w[e]); v.w = 0;
      spill[s] = v;
    }
  }
}

// ---------------- spmm row gather (shared by K2 and the fused kernel) ----------------
__device__ __forceinline__ void spmm_gather_row(
    int r, int deg, const uint2* __restrict__ bucket,
    const uint4* __restrict__ spill, int ns, const bf16_t* __restrict__ src,
    int lane, int li, int g, float* __restrict__ acc) {
#pragma unroll
  for (int c = 0; c < 16; ++c) acc[c] = 0.f;
  for (int base = 0; base < deg; base += 64) {
    const int t = base + lane;
    uint2 cw;
    cw.x = 0; cw.y = 0;
    if (t < deg) cw = bucket[(size_t)r * CAP + t];
    const int cnt = min(64, deg - base);
#pragma unroll 2
    for (int j4 = 0; j4 < cnt; j4 += 4) {
      const int cj = __shfl((int)cw.x, j4 + g);
      const float wj = __shfl(__uint_as_float(cw.y), j4 + g);
      const bf16_t* p = src + (size_t)cj * NH1 + li * 16;
      const bf16x8 v0 = *(const bf16x8*)p;
      const bf16x8 v1 = *(const bf16x8*)(p + 8);
#pragma unroll
      for (int c = 0; c < 8; ++c) {
        acc[c]     += wj * (float)v0[c];
        acc[8 + c] += wj * (float)v1[c];
      }
    }
  }
  if (ns > 0 && g == 0) {
    for (int i = 0; i < ns; ++i) {
      const uint4 s = spill[i];
      if ((int)s.x == r) {
        const float wj = __uint_as_float(s.z);
        const bf16_t* p = src + (size_t)s.y * NH1 + li * 16;
        const bf16x8 v0 = *(const bf16x8*)p;
        const bf16x8 v1 = *(const bf16x8*)(p + 8);
#pragma unroll
        for (int c = 0; c < 8; ++c) {
          acc[c]     += wj * (float)v0[c];
          acc[8 + c] += wj * (float)v1[c];
        }
      }
    }
  }
}

// ---------------- K2: h1 = relu(A . XWb) -> out f32 (nt) + h1b ----------------
__global__ __launch_bounds__(256) void spmm_bucket_relu(
    const int* __restrict__ counts, const uint2* __restrict__ bucket,
    const uint4* __restrict__ spill, const bf16_t* __restrict__ src,
    float* __restrict__ dst_f, bf16_t* __restrict__ dst_b) {
  const int lane = threadIdx.x & 63;
  const int r = blockIdx.x * 4 + (threadIdx.x >> 6);
  const int li = lane & 15;
  const int g  = lane >> 4;
  const int deg = min(counts[r], CAP);
  float acc[16];
  spmm_gather_row(r, deg, bucket, spill, counts[NN], src, lane, li, g, acc);
#pragma unroll
  for (int c = 0; c < 16; ++c) {
    acc[c] += __shfl_xor(acc[c], 16);
    acc[c] += __shfl_xor(acc[c], 32);
    acc[c] = fmaxf(acc[c], 0.f);
  }
  float o0, o1, o2, o3;
  switch (g) {
    case 0:  o0 = acc[0];  o1 = acc[1];  o2 = acc[2];  o3 = acc[3];  break;
    case 1:  o0 = acc[4];  o1 = acc[5];  o2 = acc[6];  o3 = acc[7];  break;
    case 2:  o0 = acc[8];  o1 = acc[9];  o2 = acc[10]; o3 = acc[11]; break;
    default: o0 = acc[12]; o1 = acc[13]; o2 = acc[14]; o3 = acc[15]; break;
  }
  const int ch = li * 16 + g * 4;
  floatx4 o = (floatx4){o0, o1, o2, o3};
  __builtin_nontemporal_store(o, (floatx4*)(dst_f + (size_t)r * NH1 + ch));
  bf16x4 ob;
  ob[0] = (bf16_t)o0; ob[1] = (bf16_t)o1; ob[2] = (bf16_t)o2; ob[3] = (bf16_t)o3;
  *(bf16x4*)(dst_b + (size_t)r * NH1 + ch) = ob;
}

// ---------------- K3+K4 fused: g = A.h1b (per-wave row, LDS) then
// [mu|logvar] = g @ [W2|W3] via swapped MFMA; writes mu/z/logvar f32 + zbf ----
__global__ __launch_bounds__(1024) void k_fuse23(
    const int* __restrict__ counts, const uint2* __restrict__ bucket,
    const uint4* __restrict__ spill, const bf16_t* __restrict__ h1b,
    const bf16_t* __restrict__ W23T, float* __restrict__ dout,
    bf16_t* __restrict__ zbf) {
  __shared__ bf16_t Lg[16][264];  // padded: +8 bf16 per row
  const int lane = threadIdx.x & 63;
  const int wid  = threadIdx.x >> 6;  // 0..15
  const int li = lane & 15;
  const int g  = lane >> 4;
  const int l15 = li;
  const int lg  = g;
  const int r0 = blockIdx.x * 16;
  const int r  = r0 + wid;

  // phase 1: spmm row r
  const int deg = min(counts[r], CAP);
  float acc[16];
  spmm_gather_row(r, deg, bucket, spill, counts[NN], h1b, lane, li, g, acc);
#pragma unroll
  for (int c = 0; c < 16; ++c) {
    acc[c] += __shfl_xor(acc[c], 16);
    acc[c] += __shfl_xor(acc[c], 32);
  }
  float o0, o1, o2, o3;
  switch (g) {
    case 0:  o0 = acc[0];  o1 = acc[1];  o2 = acc[2];  o3 = acc[3];  break;
    case 1:  o0 = acc[4];  o1 = acc[5];  o2 = acc[6];  o3 = acc[7];  break;
    case 2:  o0 = acc[8];  o1 = acc[9];  o2 = acc[10]; o3 = acc[11]; break;
    default: o0 = acc[12]; o1 = acc[13]; o2 = acc[14]; o3 = acc[15]; break;
  }
  bf16x4 gv;
  gv[0] = (bf16_t)o0; gv[1] = (bf16_t)o1; gv[2] = (bf16_t)o2; gv[3] = (bf16_t)o3;
  *(bf16x4*)(&Lg[wid][li * 16 + g * 4]) = gv;
  __syncthreads();

  // phase 2: wave covers output cols [wid*16, wid*16+16)
  const int wc = wid * 16;
  floatx4 a2 = (floatx4){0.f, 0.f, 0.f, 0.f};
#pragma unroll
  for (int kk = 0; kk < NH1; kk += 32) {
    const bf16x8 af = *(const bf16x8*)(&Lg[l15][kk + lg * 8]);
    const bf16x8 bw =
        *(const bf16x8*)(W23T + (size_t)(wc + l15) * NH1 + kk + lg * 8);
    a2 = __builtin_amdgcn_mfma_f32_16x16x32_bf16(bw, af, a2, 0, 0, 0);  // SWAPPED
  }
  const int orow = r0 + l15;
  const int oc = wc + lg * 4;
  if (oc < NH2) {
    __builtin_nontemporal_store(a2,
                                (floatx4*)(dout + OFF_MU + (size_t)orow * NH2 + oc));
    __builtin_nontemporal_store(a2,
                                (floatx4*)(dout + OFF_Z + (size_t)orow * NH2 + oc));
    bf16x4 ob;
    ob[0] = (bf16_t)a2[0]; ob[1] = (bf16_t)a2[1];
    ob[2] = (bf16_t)a2[2]; ob[3] = (bf16_t)a2[3];
    *(bf16x4*)(zbf + (size_t)orow * NH2 + oc) = ob;
  } else {
    __builtin_nontemporal_store(
        a2, (floatx4*)(dout + OFF_LOGVAR + (size_t)orow * NH2 + oc - NH2));
  }
}

// ---------------- adj GEMM wrapper (R7 scheme, EPI=0) ----------------
template <int KD, int RT, bool ABF, int EPI, bool SWZ>
__global__ __launch_bounds__(256) void mfma_gemm(
    const float* __restrict__ Af, const bf16_t* __restrict__ Abf,
    const bf16_t* __restrict__ BT, float* __restrict__ C, int ldc,
    bf16_t* __restrict__ zb, int ldz) {
  __shared__ float lt[4][16 * 68];
  int bx, by;
  if constexpr (SWZ) {
    const int bid = blockIdx.x;
    const int s = (bid & 7) * 512 + (bid >> 3);
    by = s >> 6; bx = s & 63;
  } else {
    bx = blockIdx.x; by = blockIdx.y;
  }
  const int lane = threadIdx.x & 63;
  const int wid  = threadIdx.x >> 6;
  gemm_body<KD, RT, ABF, EPI>(bx, by, Af, Abf, BT, C, ldc, zb, ldz, lt[wid],
                              lane, wid);
}

extern "C" void kernel_launch(void* const* d_in, const int* in_sizes, int n_in,
                              void* d_out, int out_size, void* d_ws, size_t ws_size,
                              hipStream_t stream) {
  const float* x      = (const float*)d_in[0];
  const float* W1     = (const float*)d_in[1];
  const float* W2     = (const float*)d_in[2];
  const float* W3     = (const float*)d_in[3];
  const float* edge_w = (const float*)d_in[4];
  const int*   row    = (const int*)d_in[5];
  const int*   col    = (const int*)d_in[6];
  float* out = (float*)d_out;
  char*  ws  = (char*)d_ws;

  // ws layout (~19.2 MB): zbf now separate (no overlay; fused producer reads h1b)
  bf16_t* XWb  = (bf16_t*)(ws);                           // 4 MB
  bf16_t* h1b  = (bf16_t*)(ws + (4u << 20));              // 4 MB
  bf16_t* W1T  = (bf16_t*)(ws + (8u << 20));              // 256 KB
  bf16_t* W23T = (bf16_t*)(ws + (8u << 20) + (1u << 18)); // 128 KB
  int*    counts = (int*)(ws + (8u << 20) + (3u << 18));  // (NN+1)*4B
  uint2*  bucket = (uint2*)(ws + (9u << 20));             // 8 MB (CAP=128)
  uint4*  spill  = (uint4*)(ws + (17u << 20));            // 64 KB
  bf16_t* zbf  = (bf16_t*)(ws + (17u << 20) + (1u << 16)); // 2 MB

  // K0: zero counts + weight transpose
  k_prep<<<512, 256, 0, stream>>>(W1, W2, W3, W1T, W23T, counts);
  // K1: gemm1 (XWb = bf16(x@W1)) || bucket fill
  k_fat<<<1280, 256, 0, stream>>>(x, W1T, XWb, row, col, edge_w, counts, bucket,
                                  spill);
  // K2: h1 = relu(A . XWb) -> out f32 (nt) + h1b
  spmm_bucket_relu<<<NN / 4, 256, 0, stream>>>(counts, bucket, spill, XWb,
                                               out + OFF_H1, h1b);
  // K3+K4 fused: g = A.h1b (LDS) -> [mu|logvar] = g@[W2|W3]; zbf bf16
  k_fuse23<<<NN / 16, 1024, 0, stream>>>(counts, bucket, spill, h1b, W23T, out,
                                         zbf);
  // K5: adj = z @ z^T (R7 scheme, XCD-swizzled, LDS-transposed 256B nt stores)
  mfma_gemm<NH2, 4, true, 0, true><<<4096, 256, 0, stream>>>(
      nullptr, zbf, zbf, out + OFF_ADJ, NN, nullptr, 0);
}

// Round 16
// 127.905 us; speedup vs baseline: 1.3025x; 1.0860x over previous
//
#include <hip/hip_runtime.h>

typedef __bf16 bf16_t;
typedef __bf16 bf16x4 __attribute__((ext_vector_type(4)));
typedef __bf16 bf16x8 __attribute__((ext_vector_type(8)));
typedef float floatx4 __attribute__((ext_vector_type(4)));

static constexpr int NN  = 8192;
static constexpr int FIN = 512;
static constexpr int NH1 = 256;
static constexpr int NH2 = 128;
static constexpr int NE  = 262144;
static constexpr int CAP = 128;   // bucket capacity per row (mean deg 32, P(>128)~e^-70)

// output layout (floats): h1, adj_rec, mu, logvar, z
static constexpr size_t OFF_H1     = 0;
static constexpr size_t OFF_ADJ    = (size_t)NN * NH1;
static constexpr size_t OFF_MU     = OFF_ADJ + (size_t)NN * NN;
static constexpr size_t OFF_LOGVAR = OFF_MU + (size_t)NN * NH2;
static constexpr size_t OFF_Z      = OFF_LOGVAR + (size_t)NN * NH2;

// ---------------- GEMM body (bf16 MFMA, f32 acc) ---- R7 exact ----
// EPI: 2 = bf16 only (XWb)
template <int KD, int RT, bool ABF, int EPI>
__device__ __forceinline__ void gemm_body(
    int bx, int by, const float* __restrict__ Af, const bf16_t* __restrict__ Abf,
    const bf16_t* __restrict__ BT, float* __restrict__ C, int ldc,
    bf16_t* __restrict__ zb, int ldz, float* __restrict__ L, int lane, int wid) {
  const int l15 = lane & 15;
  const int lg  = lane >> 4;
  const int brow = by * (RT * 32) + (wid >> 1) * (RT * 16);
  const int bcol = bx * 128 + (wid & 1) * 64;

  floatx4 acc[RT][4];
#pragma unroll
  for (int i = 0; i < RT; ++i)
#pragma unroll
    for (int j = 0; j < 4; ++j) acc[i][j] = (floatx4){0.f, 0.f, 0.f, 0.f};

#pragma unroll 1
  for (int kk = 0; kk < KD; kk += 32) {
    bf16x8 a[RT], b[4];
#pragma unroll
    for (int rt = 0; rt < RT; ++rt) {
      const int r = brow + rt * 16 + l15;
      if constexpr (ABF) {
        a[rt] = *(const bf16x8*)(Abf + (size_t)r * KD + kk + lg * 8);
      } else {
        const float* p = Af + (size_t)r * KD + kk + lg * 8;
        const floatx4 lo = *(const floatx4*)p;
        const floatx4 hi = *(const floatx4*)(p + 4);
        bf16x8 t;
        t[0] = (bf16_t)lo[0]; t[1] = (bf16_t)lo[1];
        t[2] = (bf16_t)lo[2]; t[3] = (bf16_t)lo[3];
        t[4] = (bf16_t)hi[0]; t[5] = (bf16_t)hi[1];
        t[6] = (bf16_t)hi[2]; t[7] = (bf16_t)hi[3];
        a[rt] = t;
      }
    }
#pragma unroll
    for (int ct = 0; ct < 4; ++ct) {
      const int c = bcol + ct * 16 + l15;
      b[ct] = *(const bf16x8*)(BT + (size_t)c * KD + kk + lg * 8);
    }
#pragma unroll
    for (int rt = 0; rt < RT; ++rt)
#pragma unroll
      for (int ct = 0; ct < 4; ++ct)
        acc[rt][ct] = __builtin_amdgcn_mfma_f32_16x16x32_bf16(
            a[rt], b[ct], acc[rt][ct], 0, 0, 0);
  }

#pragma unroll
  for (int rt = 0; rt < RT; ++rt) {
#pragma unroll
    for (int ct = 0; ct < 4; ++ct)
#pragma unroll
      for (int r = 0; r < 4; ++r)
        L[(lg * 4 + r) * 68 + ct * 16 + l15] = acc[rt][ct][r];
    __builtin_amdgcn_wave_barrier();
#pragma unroll
    for (int it = 0; it < 4; ++it) {
      const int idx = it * 64 + lane;
      const int rr = idx >> 4, c4 = idx & 15;
      const floatx4 v = *(const floatx4*)(L + rr * 68 + c4 * 4);
      const int orow = brow + rt * 16 + rr;
      const int gc = bcol + c4 * 4;
      bf16x4 o;
      o[0] = (bf16_t)v[0]; o[1] = (bf16_t)v[1];
      o[2] = (bf16_t)v[2]; o[3] = (bf16_t)v[3];
      *(bf16x4*)(zb + (size_t)orow * ldz + gc) = o;
    }
    __builtin_amdgcn_wave_barrier();
  }
}

// ---------------- K0: zero counts/spill + weight transpose to bf16 ----------------
__global__ __launch_bounds__(256) void k_prep(
    const float* __restrict__ W1, const float* __restrict__ W2,
    const float* __restrict__ W3, bf16_t* __restrict__ W1T,
    bf16_t* __restrict__ W23T, int* __restrict__ counts) {
  const int gid = blockIdx.x * 256 + threadIdx.x;
  if (gid <= NN) counts[gid] = 0;
  if (gid < NH1 * FIN) {
    const int n = gid >> 9, k = gid & 511;
    W1T[gid] = (bf16_t)W1[k * NH1 + n];
  }
  if (gid < NH1 * NH1) {
    const int n = gid >> 8, k = gid & 255;
    W23T[gid] = (bf16_t)(n < NH2 ? W2[k * NH2 + n] : W3[k * NH2 + (n - NH2)]);
  }
}

// ---------------- K1 fat: gemm1 (blocks 0..255) || bucket fill (256..1279) ----------------
__global__ __launch_bounds__(256) void k_fat(
    const float* __restrict__ x, const bf16_t* __restrict__ W1T,
    bf16_t* __restrict__ XWb, const int* __restrict__ row,
    const int* __restrict__ col, const float* __restrict__ edge_w,
    int* __restrict__ counts, uint2* __restrict__ bucket,
    uint4* __restrict__ spill) {
  __shared__ float lt[4][16 * 68];
  const int bid = blockIdx.x;
  if (bid < 256) {
    const int lane = threadIdx.x & 63;
    const int wid  = threadIdx.x >> 6;
    gemm_body<FIN, 2, false, 2>(bid & 1, bid >> 1, x, nullptr, W1T, nullptr, 0,
                                XWb, NH1, lt[wid], lane, wid);
  } else {
    const int e = (bid - 256) * 256 + threadIdx.x;
    const int r = row[e];
    const int p = atomicAdd(&counts[r], 1);
    if (p < CAP) {
      uint2 v;
      v.x = (unsigned)col[e];
      v.y = __float_as_uint(edge_w[e]);
      bucket[(size_t)r * CAP + p] = v;
    } else {
      const int s = atomicAdd(&counts[NN], 1);
      uint4 v;
      v.x = (unsigned)r; v.y = (unsigned)col[e];
      v.z = __float_as_uint(edge_w[e]); v.w = 0;
      spill[s] = v;
    }
  }
}

// ---------------- spmm row gather (shared) ----------------
__device__ __forceinline__ void spmm_gather_row(
    int r, int deg, const uint2* __restrict__ bucket,
    const uint4* __restrict__ spill, int ns, const bf16_t* __restrict__ src,
    int lane, int li, int g, float* __restrict__ acc) {
#pragma unroll
  for (int c = 0; c < 16; ++c) acc[c] = 0.f;
  for (int base = 0; base < deg; base += 64) {
    const int t = base + lane;
    uint2 cw;
    cw.x = 0; cw.y = 0;
    if (t < deg) cw = bucket[(size_t)r * CAP + t];
    const int cnt = min(64, deg - base);
#pragma unroll 2
    for (int j4 = 0; j4 < cnt; j4 += 4) {
      const int cj = __shfl((int)cw.x, j4 + g);
      const float wj = __shfl(__uint_as_float(cw.y), j4 + g);
      const bf16_t* p = src + (size_t)cj * NH1 + li * 16;
      const bf16x8 v0 = *(const bf16x8*)p;
      const bf16x8 v1 = *(const bf16x8*)(p + 8);
#pragma unroll
      for (int c = 0; c < 8; ++c) {
        acc[c]     += wj * (float)v0[c];
        acc[8 + c] += wj * (float)v1[c];
      }
    }
  }
  if (ns > 0 && g == 0) {
    for (int i = 0; i < ns; ++i) {
      const uint4 s = spill[i];
      if ((int)s.x == r) {
        const float wj = __uint_as_float(s.z);
        const bf16_t* p = src + (size_t)s.y * NH1 + li * 16;
        const bf16x8 v0 = *(const bf16x8*)p;
        const bf16x8 v1 = *(const bf16x8*)(p + 8);
#pragma unroll
        for (int c = 0; c < 8; ++c) {
          acc[c]     += wj * (float)v0[c];
          acc[8 + c] += wj * (float)v1[c];
        }
      }
    }
  }
}

// ---------------- K2: h1 = relu(A . XWb) -> out f32 (nt) + h1b ----------------
__global__ __launch_bounds__(256) void spmm_bucket_relu(
    const int* __restrict__ counts, const uint2* __restrict__ bucket,
    const uint4* __restrict__ spill, const bf16_t* __restrict__ src,
    float* __restrict__ dst_f, bf16_t* __restrict__ dst_b) {
  const int lane = threadIdx.x & 63;
  const int r = blockIdx.x * 4 + (threadIdx.x >> 6);
  const int li = lane & 15;
  const int g  = lane >> 4;
  const int deg = min(counts[r], CAP);
  float acc[16];
  spmm_gather_row(r, deg, bucket, spill, counts[NN], src, lane, li, g, acc);
#pragma unroll
  for (int c = 0; c < 16; ++c) {
    acc[c] += __shfl_xor(acc[c], 16);
    acc[c] += __shfl_xor(acc[c], 32);
    acc[c] = fmaxf(acc[c], 0.f);
  }
  float o0, o1, o2, o3;
  switch (g) {
    case 0:  o0 = acc[0];  o1 = acc[1];  o2 = acc[2];  o3 = acc[3];  break;
    case 1:  o0 = acc[4];  o1 = acc[5];  o2 = acc[6];  o3 = acc[7];  break;
    case 2:  o0 = acc[8];  o1 = acc[9];  o2 = acc[10]; o3 = acc[11]; break;
    default: o0 = acc[12]; o1 = acc[13]; o2 = acc[14]; o3 = acc[15]; break;
  }
  const int ch = li * 16 + g * 4;
  floatx4 o = (floatx4){o0, o1, o2, o3};
  __builtin_nontemporal_store(o, (floatx4*)(dst_f + (size_t)r * NH1 + ch));
  bf16x4 ob;
  ob[0] = (bf16_t)o0; ob[1] = (bf16_t)o1; ob[2] = (bf16_t)o2; ob[3] = (bf16_t)o3;
  *(bf16x4*)(dst_b + (size_t)r * NH1 + ch) = ob;
}

// ---------------- K3+K4 fused: g = A.h1b (LDS) -> [mu|logvar] = g@[W2|W3] ----------------
__global__ __launch_bounds__(1024) void k_fuse23(
    const int* __restrict__ counts, const uint2* __restrict__ bucket,
    const uint4* __restrict__ spill, const bf16_t* __restrict__ h1b,
    const bf16_t* __restrict__ W23T, float* __restrict__ dout,
    bf16_t* __restrict__ zbf) {
  __shared__ bf16_t Lg[16][264];
  const int lane = threadIdx.x & 63;
  const int wid  = threadIdx.x >> 6;
  const int li = lane & 15;
  const int g  = lane >> 4;
  const int l15 = li;
  const int lg  = g;
  const int r0 = blockIdx.x * 16;
  const int r  = r0 + wid;

  const int deg = min(counts[r], CAP);
  float acc[16];
  spmm_gather_row(r, deg, bucket, spill, counts[NN], h1b, lane, li, g, acc);
#pragma unroll
  for (int c = 0; c < 16; ++c) {
    acc[c] += __shfl_xor(acc[c], 16);
    acc[c] += __shfl_xor(acc[c], 32);
  }
  float o0, o1, o2, o3;
  switch (g) {
    case 0:  o0 = acc[0];  o1 = acc[1];  o2 = acc[2];  o3 = acc[3];  break;
    case 1:  o0 = acc[4];  o1 = acc[5];  o2 = acc[6];  o3 = acc[7];  break;
    case 2:  o0 = acc[8];  o1 = acc[9];  o2 = acc[10]; o3 = acc[11]; break;
    default: o0 = acc[12]; o1 = acc[13]; o2 = acc[14]; o3 = acc[15]; break;
  }
  bf16x4 gv;
  gv[0] = (bf16_t)o0; gv[1] = (bf16_t)o1; gv[2] = (bf16_t)o2; gv[3] = (bf16_t)o3;
  *(bf16x4*)(&Lg[wid][li * 16 + g * 4]) = gv;
  __syncthreads();

  const int wc = wid * 16;
  floatx4 a2 = (floatx4){0.f, 0.f, 0.f, 0.f};
#pragma unroll
  for (int kk = 0; kk < NH1; kk += 32) {
    const bf16x8 af = *(const bf16x8*)(&Lg[l15][kk + lg * 8]);
    const bf16x8 bw =
        *(const bf16x8*)(W23T + (size_t)(wc + l15) * NH1 + kk + lg * 8);
    a2 = __builtin_amdgcn_mfma_f32_16x16x32_bf16(bw, af, a2, 0, 0, 0);  // SWAPPED
  }
  const int orow = r0 + l15;
  const int oc = wc + lg * 4;
  if (oc < NH2) {
    __builtin_nontemporal_store(a2,
                                (floatx4*)(dout + OFF_MU + (size_t)orow * NH2 + oc));
    __builtin_nontemporal_store(a2,
                                (floatx4*)(dout + OFF_Z + (size_t)orow * NH2 + oc));
    bf16x4 ob;
    ob[0] = (bf16_t)a2[0]; ob[1] = (bf16_t)a2[1];
    ob[2] = (bf16_t)a2[2]; ob[3] = (bf16_t)a2[3];
    *(bf16x4*)(zbf + (size_t)orow * NH2 + oc) = ob;
  } else {
    __builtin_nontemporal_store(
        a2, (floatx4*)(dout + OFF_LOGVAR + (size_t)orow * NH2 + oc - NH2));
  }
}

// ---------------- K5: adj slab-walk kernel ----------------
// 512 blocks (2/CU): block = 64 rows x 2048 cols; wave = 64 rows x 512 cols.
// A-panel (64x128) cached in regs; ct-loop walks 16-col tiles; every 4 tiles
// flush 64x64 f32 via LDS (R7 transpose layout) as 256B nt segments.
// Each row's 512-col window is written time-sequentially by one wave -> ~8x
// fewer DRAM page-opens than the 128x128-tile grid.
__global__ __launch_bounds__(256) void adj_slab(
    const bf16_t* __restrict__ zb, float* __restrict__ C) {
  __shared__ float lt[4][64 * 68];  // 69632 B -> 2 blocks/CU
  const int bid = blockIdx.x;
  const int s = (bid & 7) * 64 + (bid >> 3);  // XCD-contiguous
  const int rp = s >> 2, cs = s & 3;
  const int lane = threadIdx.x & 63;
  const int wid  = threadIdx.x >> 6;
  const int l15 = lane & 15;
  const int lg  = lane >> 4;
  const int r0 = rp * 64;
  const int c0 = cs * 2048 + wid * 512;
  float* L = lt[wid];

  // cache A-panel 64x128 in registers (16 x bf16x8)
  bf16x8 a_[4][4];
#pragma unroll
  for (int rt = 0; rt < 4; ++rt)
#pragma unroll
    for (int ks = 0; ks < 4; ++ks)
      a_[rt][ks] = *(const bf16x8*)(zb + (size_t)(r0 + rt * 16 + l15) * NH2 +
                                    ks * 32 + lg * 8);

#pragma unroll 1
  for (int ctg = 0; ctg < 8; ++ctg) {
    const int cgbase = c0 + ctg * 64;
#pragma unroll
    for (int ctm = 0; ctm < 4; ++ctm) {
      const int c = cgbase + ctm * 16 + l15;
      bf16x8 b_[4];
#pragma unroll
      for (int ks = 0; ks < 4; ++ks)
        b_[ks] = *(const bf16x8*)(zb + (size_t)c * NH2 + ks * 32 + lg * 8);
#pragma unroll
      for (int rt = 0; rt < 4; ++rt) {
        floatx4 acc = (floatx4){0.f, 0.f, 0.f, 0.f};
#pragma unroll
        for (int ks = 0; ks < 4; ++ks)
          acc = __builtin_amdgcn_mfma_f32_16x16x32_bf16(a_[rt][ks], b_[ks], acc,
                                                        0, 0, 0);
#pragma unroll
        for (int r = 0; r < 4; ++r)
          L[(rt * 16 + lg * 4 + r) * 68 + ctm * 16 + l15] = acc[r];
      }
    }
    __builtin_amdgcn_wave_barrier();
#pragma unroll
    for (int it = 0; it < 16; ++it) {
      const int rr = it * 4 + lg;
      const floatx4 v = *(const floatx4*)(L + rr * 68 + l15 * 4);
      __builtin_nontemporal_store(
          v, (floatx4*)(C + (size_t)(r0 + rr) * NN + cgbase + l15 * 4));
    }
    __builtin_amdgcn_wave_barrier();
  }
}

extern "C" void kernel_launch(void* const* d_in, const int* in_sizes, int n_in,
                              void* d_out, int out_size, void* d_ws, size_t ws_size,
                              hipStream_t stream) {
  const float* x      = (const float*)d_in[0];
  const float* W1     = (const float*)d_in[1];
  const float* W2     = (const float*)d_in[2];
  const float* W3     = (const float*)d_in[3];
  const float* edge_w = (const float*)d_in[4];
  const int*   row    = (const int*)d_in[5];
  const int*   col    = (const int*)d_in[6];
  float* out = (float*)d_out;
  char*  ws  = (char*)d_ws;

  bf16_t* XWb  = (bf16_t*)(ws);                           // 4 MB
  bf16_t* h1b  = (bf16_t*)(ws + (4u << 20));              // 4 MB
  bf16_t* W1T  = (bf16_t*)(ws + (8u << 20));              // 256 KB
  bf16_t* W23T = (bf16_t*)(ws + (8u << 20) + (1u << 18)); // 128 KB
  int*    counts = (int*)(ws + (8u << 20) + (3u << 18));  // (NN+1)*4B
  uint2*  bucket = (uint2*)(ws + (9u << 20));             // 8 MB (CAP=128)
  uint4*  spill  = (uint4*)(ws + (17u << 20));            // 64 KB
  bf16_t* zbf  = (bf16_t*)(ws + (17u << 20) + (1u << 16)); // 2 MB

  // K0: zero counts + weight transpose
  k_prep<<<512, 256, 0, stream>>>(W1, W2, W3, W1T, W23T, counts);
  // K1: gemm1 (XWb = bf16(x@W1)) || bucket fill
  k_fat<<<1280, 256, 0, stream>>>(x, W1T, XWb, row, col, edge_w, counts, bucket,
                                  spill);
  // K2: h1 = relu(A . XWb) -> out f32 (nt) + h1b
  spmm_bucket_relu<<<NN / 4, 256, 0, stream>>>(counts, bucket, spill, XWb,
                                               out + OFF_H1, h1b);
  // K3+K4 fused
  k_fuse23<<<NN / 16, 1024, 0, stream>>>(counts, bucket, spill, h1b, W23T, out,
                                         zbf);
  // K5: adj = z @ z^T, slab-walk page-sequential writes
  adj_slab<<<512, 256, 0, stream>>>(zbf, out + OFF_ADJ);
}